// Round 6
// baseline (8716.882 us; speedup 1.0000x reference)
//
#include <hip/hip_runtime.h>
#include <cfloat>

#define BB 16
#define DD 512
#define TT 2048
#define QQ 8
#define NN 1024
#define MM 16
#define RS 520  // resid LDS row stride in floats (16B-aligned, bank-staggered)

// numpy pairwise_sum (scalar path) of squares over 512 contiguous floats:
// base-128 = 8 accumulator chains, combine ((r0+r1)+(r2+r3))+((r4+r5)+(r6+r7));
// 512 = (b0+b1)+(b2+b3). No FMA anywhere (__fmul_rn/__fadd_rn).
__device__ __forceinline__ float np_block128_sq(const float* a) {
    float r[8];
    #pragma unroll
    for (int j = 0; j < 8; ++j) r[j] = __fmul_rn(a[j], a[j]);
    #pragma unroll
    for (int i = 8; i < 128; i += 8)
        #pragma unroll
        for (int j = 0; j < 8; ++j) r[j] = __fadd_rn(r[j], __fmul_rn(a[i + j], a[i + j]));
    return __fadd_rn(__fadd_rn(__fadd_rn(r[0], r[1]), __fadd_rn(r[2], r[3])),
                     __fadd_rn(__fadd_rn(r[4], r[5]), __fadd_rn(r[6], r[7])));
}
__device__ __forceinline__ float np_sum_sq_512(const float* p) {
    const float b0 = np_block128_sq(p);
    const float b1 = np_block128_sq(p + 128);
    const float b2 = np_block128_sq(p + 256);
    const float b3 = np_block128_sq(p + 384);
    return __fadd_rn(__fadd_rn(b0, b1), __fadd_rn(b2, b3));
}

__global__ __launch_bounds__(64) void rvq_init(double* lossws) {
    if (threadIdx.x < QQ) lossws[threadIdx.x] = 0.0;
}

// ||c||^2 per (q,n), numpy np.sum(cb*cb, -1) pairwise semantics
__global__ __launch_bounds__(256) void rvq_cnorm(const float* __restrict__ cbs,
                                                 float* __restrict__ cnorm) {
    const int gid = blockIdx.x * 256 + threadIdx.x;  // 0..8191
    cnorm[gid] = np_sum_sq_512(cbs + (size_t)gid * DD);
}

// Residual VQ argmin, replicating numpy float32 semantics.
__global__ __launch_bounds__(256) void rvq_argmin(const float* __restrict__ z,
                                                  const float* __restrict__ cbs,
                                                  const float* __restrict__ cnorm,
                                                  int* __restrict__ codes_ws) {
    __shared__ float resid[MM * RS];    // [m][d], fp32
    __shared__ float A_sh[MM];
    __shared__ int   sel[MM];
    __shared__ float redv[MM * 128];
    __shared__ int   redi[MM * 128];

    const int tid = threadIdx.x;
    const int blk = blockIdx.x;          // 0..2047
    const int b   = blk >> 7;
    const int t0  = (blk & 127) * MM;
    const float* zb = z + (size_t)b * DD * TT + t0;

    for (int p = 0; p < 32; ++p) {
        const int d = (tid >> 4) + p * 16;
        const int m = tid & 15;
        resid[m * RS + d] = zb[(size_t)d * TT + m];
    }
    __syncthreads();
    if (tid < MM) A_sh[tid] = np_sum_sq_512(resid + tid * RS);

    const int half  = tid >> 7;          // m-half
    const int nl    = tid & 127;
    const int mbase = half * 8;

    for (int q = 0; q < QQ; ++q) {
        __syncthreads();                 // A_sh ready, resid stable, redv free
        const float* cbq = cbs + (size_t)q * NN * DD;

        float bv[8]; int bi[8];
        #pragma unroll
        for (int i = 0; i < 8; ++i) { bv[i] = FLT_MAX; bi[i] = 0; }

        for (int nb = 0; nb < 2; ++nb) {
            const int n0 = nb * 512 + nl;
            const float* c0 = cbq + (size_t)(n0      ) * DD;
            const float* c1 = cbq + (size_t)(n0 + 128) * DD;
            const float* c2 = cbq + (size_t)(n0 + 256) * DD;
            const float* c3 = cbq + (size_t)(n0 + 384) * DD;

            float4 acc[8][4];            // [m][n-slot], float4 lanes = k%4 chains (SSE einsum)
            #pragma unroll
            for (int m = 0; m < 8; ++m)
                #pragma unroll
                for (int j = 0; j < 4; ++j) acc[m][j] = make_float4(0.f, 0.f, 0.f, 0.f);

            const float* rb = resid + mbase * RS;

            for (int k8 = 0; k8 < 64; ++k8) {
                const int ko = k8 * 8;
                const float4 w0a = *(const float4*)(c0 + ko), w0b = *(const float4*)(c0 + ko + 4);
                const float4 w1a = *(const float4*)(c1 + ko), w1b = *(const float4*)(c1 + ko + 4);
                const float4 w2a = *(const float4*)(c2 + ko), w2b = *(const float4*)(c2 + ko + 4);
                const float4 w3a = *(const float4*)(c3 + ko), w3b = *(const float4*)(c3 + ko + 4);
                #pragma unroll
                for (int m = 0; m < 8; ++m) {
                    const float4 r0 = *(const float4*)(rb + m * RS + ko);
                    const float4 r1 = *(const float4*)(rb + m * RS + ko + 4);
                    // chain j = k%4: add product at k then k+4 (ascending), mul+add (no FMA)
                    acc[m][0].x = __fadd_rn(acc[m][0].x, __fmul_rn(r0.x, w0a.x));
                    acc[m][0].y = __fadd_rn(acc[m][0].y, __fmul_rn(r0.y, w0a.y));
                    acc[m][0].z = __fadd_rn(acc[m][0].z, __fmul_rn(r0.z, w0a.z));
                    acc[m][0].w = __fadd_rn(acc[m][0].w, __fmul_rn(r0.w, w0a.w));
                    acc[m][0].x = __fadd_rn(acc[m][0].x, __fmul_rn(r1.x, w0b.x));
                    acc[m][0].y = __fadd_rn(acc[m][0].y, __fmul_rn(r1.y, w0b.y));
                    acc[m][0].z = __fadd_rn(acc[m][0].z, __fmul_rn(r1.z, w0b.z));
                    acc[m][0].w = __fadd_rn(acc[m][0].w, __fmul_rn(r1.w, w0b.w));
                    acc[m][1].x = __fadd_rn(acc[m][1].x, __fmul_rn(r0.x, w1a.x));
                    acc[m][1].y = __fadd_rn(acc[m][1].y, __fmul_rn(r0.y, w1a.y));
                    acc[m][1].z = __fadd_rn(acc[m][1].z, __fmul_rn(r0.z, w1a.z));
                    acc[m][1].w = __fadd_rn(acc[m][1].w, __fmul_rn(r0.w, w1a.w));
                    acc[m][1].x = __fadd_rn(acc[m][1].x, __fmul_rn(r1.x, w1b.x));
                    acc[m][1].y = __fadd_rn(acc[m][1].y, __fmul_rn(r1.y, w1b.y));
                    acc[m][1].z = __fadd_rn(acc[m][1].z, __fmul_rn(r1.z, w1b.z));
                    acc[m][1].w = __fadd_rn(acc[m][1].w, __fmul_rn(r1.w, w1b.w));
                    acc[m][2].x = __fadd_rn(acc[m][2].x, __fmul_rn(r0.x, w2a.x));
                    acc[m][2].y = __fadd_rn(acc[m][2].y, __fmul_rn(r0.y, w2a.y));
                    acc[m][2].z = __fadd_rn(acc[m][2].z, __fmul_rn(r0.z, w2a.z));
                    acc[m][2].w = __fadd_rn(acc[m][2].w, __fmul_rn(r0.w, w2a.w));
                    acc[m][2].x = __fadd_rn(acc[m][2].x, __fmul_rn(r1.x, w2b.x));
                    acc[m][2].y = __fadd_rn(acc[m][2].y, __fmul_rn(r1.y, w2b.y));
                    acc[m][2].z = __fadd_rn(acc[m][2].z, __fmul_rn(r1.z, w2b.z));
                    acc[m][2].w = __fadd_rn(acc[m][2].w, __fmul_rn(r1.w, w2b.w));
                    acc[m][3].x = __fadd_rn(acc[m][3].x, __fmul_rn(r0.x, w3a.x));
                    acc[m][3].y = __fadd_rn(acc[m][3].y, __fmul_rn(r0.y, w3a.y));
                    acc[m][3].z = __fadd_rn(acc[m][3].z, __fmul_rn(r0.z, w3a.z));
                    acc[m][3].w = __fadd_rn(acc[m][3].w, __fmul_rn(r0.w, w3a.w));
                    acc[m][3].x = __fadd_rn(acc[m][3].x, __fmul_rn(r1.x, w3b.x));
                    acc[m][3].y = __fadd_rn(acc[m][3].y, __fmul_rn(r1.y, w3b.y));
                    acc[m][3].z = __fadd_rn(acc[m][3].z, __fmul_rn(r1.z, w3b.z));
                    acc[m][3].w = __fadd_rn(acc[m][3].w, __fmul_rn(r1.w, w3b.w));
                }
            }
            // scores: d2 = fl(fl(A - fl(2E)) + C); E = SSE horizontal (l0+l2)+(l1+l3)
            #pragma unroll
            for (int j = 0; j < 4; ++j) {
                const int n = n0 + j * 128;
                const float Cn = cnorm[q * NN + n];
                #pragma unroll
                for (int m = 0; m < 8; ++m) {
                    const float4 a = acc[m][j];
                    const float E = __fadd_rn(__fadd_rn(a.x, a.z), __fadd_rn(a.y, a.w));
                    const float s = __fadd_rn(__fsub_rn(A_sh[mbase + m], __fmul_rn(2.0f, E)), Cn);
                    if (s < bv[m]) { bv[m] = s; bi[m] = n; }  // n ascending per thread -> first-min
                }
            }
        }

        __syncthreads();
        #pragma unroll
        for (int m = 0; m < 8; ++m) {
            redv[(mbase + m) * 128 + nl] = bv[m];
            redi[(mbase + m) * 128 + nl] = bi[m];
        }
        __syncthreads();
        {
            const int m = tid >> 4, j0 = tid & 15;
            float v  = redv[m * 128 + j0];
            int   ix = redi[m * 128 + j0];
            for (int u = 1; u < 8; ++u) {
                const float v2 = redv[m * 128 + j0 + 16 * u];
                const int   i2 = redi[m * 128 + j0 + 16 * u];
                if (v2 < v || (v2 == v && i2 < ix)) { v = v2; ix = i2; }
            }
            #pragma unroll
            for (int mask = 1; mask < 16; mask <<= 1) {
                const float v2 = __shfl_xor(v, mask, 64);
                const int   i2 = __shfl_xor(ix, mask, 64);
                if (v2 < v || (v2 == v && i2 < ix)) { v = v2; ix = i2; }
            }
            if (j0 == 0) {
                sel[m] = ix;
                codes_ws[b * QQ * TT + q * TT + t0 + m] = ix;
            }
        }
        __syncthreads();

        if (q < QQ - 1) {
            const int m = tid >> 4, l16 = tid & 15;
            const float* cr = cbq + (size_t)sel[m] * DD;
            for (int jj = 0; jj < 32; ++jj) {
                const int d = l16 + jj * 16;
                resid[m * RS + d] = __fsub_rn(resid[m * RS + d], cr[d]);
            }
            __syncthreads();
            if (tid < MM) A_sh[tid] = np_sum_sq_512(resid + tid * RS);
        }
    }
}

// Rebuild: quantized = sequential fp32 sum of chosen codewords (np order),
// codes as float, per-stage loss partials. FP32 output buffer.
__global__ __launch_bounds__(256) void rvq_build(const float* __restrict__ z,
                                                 const float* __restrict__ cbs,
                                                 const int* __restrict__ codes_ws,
                                                 float* __restrict__ out,
                                                 double* __restrict__ lossws) {
    __shared__ int    lcode[MM * QQ];
    __shared__ double lpart[4][QQ];

    const int tid = threadIdx.x;
    const int blk = blockIdx.x;
    const int b   = blk >> 7;
    const int t0  = (blk & 127) * MM;

    if (tid < MM * QQ) {
        const int m = tid >> 3;
        const int q = tid & 7;
        const int c = codes_ws[b * QQ * TT + q * TT + t0 + m];
        lcode[tid] = c;
        out[(size_t)BB * DD * TT + (size_t)b * QQ * TT + (size_t)q * TT + t0 + m] = (float)c;
    }
    __syncthreads();

    const int m  = tid & 15;
    const int dl = tid >> 4;

    double lsum[QQ];
    #pragma unroll
    for (int q = 0; q < QQ; ++q) lsum[q] = 0.0;

    for (int p = 0; p < DD / 16; ++p) {
        const int d = dl + p * 16;
        float r  = z[(size_t)b * DD * TT + (size_t)d * TT + t0 + m];
        float qa = 0.0f;
        #pragma unroll
        for (int q = 0; q < QQ; ++q) {
            const float c = cbs[(size_t)q * NN * DD + (size_t)lcode[m * 8 + q] * DD + d];
            qa = __fadd_rn(qa, c);
            r  = __fsub_rn(r, c);
            lsum[q] += (double)r * (double)r;
        }
        out[(size_t)b * DD * TT + (size_t)d * TT + t0 + m] = qa;
    }

    const int wid = tid >> 6, lane = tid & 63;
    #pragma unroll
    for (int q = 0; q < QQ; ++q) {
        double v = lsum[q];
        #pragma unroll
        for (int off = 32; off > 0; off >>= 1) v += __shfl_down(v, off, 64);
        lsum[q] = v;
    }
    if (lane == 0) {
        #pragma unroll
        for (int q = 0; q < QQ; ++q) lpart[wid][q] = lsum[q];
    }
    __syncthreads();
    if (tid < QQ) {
        const double s = lpart[0][tid] + lpart[1][tid] + lpart[2][tid] + lpart[3][tid];
        atomicAdd(&lossws[tid], s);
    }
}

__global__ __launch_bounds__(64) void rvq_final(const double* __restrict__ lossws,
                                                float* __restrict__ out) {
    if (threadIdx.x == 0) {
        double tot = 0.0;
        for (int q = 0; q < QQ; ++q) {
            double c = lossws[q] / (double)((size_t)BB * TT * DD);
            c = c < 0.0 ? 0.0 : (c > 10.0 ? 10.0 : c);
            tot += 0.25 * c;
        }
        tot = tot < 0.0 ? 0.0 : (tot > 10.0 ? 10.0 : tot);
        out[(size_t)BB * DD * TT + (size_t)BB * QQ * TT] = (float)tot;
    }
}

extern "C" void kernel_launch(void* const* d_in, const int* in_sizes, int n_in,
                              void* d_out, int out_size, void* d_ws, size_t ws_size,
                              hipStream_t stream) {
    const float* z   = (const float*)d_in[0];
    const float* cbs = (const float*)d_in[1];
    float* out       = (float*)d_out;
    double* lossws   = (double*)d_ws;
    float* cnorm     = (float*)((char*)d_ws + 64);
    int* codes_ws    = (int*)((char*)d_ws + 64 + QQ * NN * 4);

    rvq_init  <<<1, 64, 0, stream>>>(lossws);
    rvq_cnorm <<<QQ * NN / 256, 256, 0, stream>>>(cbs, cnorm);
    rvq_argmin<<<BB * (TT / MM), 256, 0, stream>>>(z, cbs, cnorm, codes_ws);
    rvq_build <<<BB * (TT / MM), 256, 0, stream>>>(z, cbs, codes_ws, out, lossws);
    rvq_final <<<1, 64, 0, stream>>>(lossws, out);
}